// Round 1
// baseline (628.199 us; speedup 1.0000x reference)
//
#include <hip/hip_runtime.h>

#define MARGIN 0.1f
#define BB 256
#define CC 4096
#define DD 100
#define CBLK 256   // c-values per block (grid.y = CC/CBLK = 16)

// ---------------- loss1: mean((pos - lan)^2) over B*D; also initializes d_out ----------------
__global__ __launch_bounds__(256) void loss1_kernel(const float* __restrict__ pos,
                                                    const float* __restrict__ lan,
                                                    float* __restrict__ out) {
    const int tid = threadIdx.x;
    const int N = BB * DD;  // 25600
    float s = 0.f;
    for (int i = tid; i < N; i += 256) {
        float d = pos[i] - lan[i];
        s += d * d;
    }
    #pragma unroll
    for (int off = 32; off >= 1; off >>= 1)
        s += __shfl_xor(s, off, 64);
    __shared__ float ws[4];
    const int w = tid >> 6;
    if ((tid & 63) == 0) ws[w] = s;
    __syncthreads();
    if (tid == 0) {
        float t = ws[0] + ws[1] + ws[2] + ws[3];
        out[0] = t * (1.f / (float)N);   // overwrite: doubles as output init each call
    }
}

// ---------------- loss2: mean(relu(MARGIN - mean_d (pos-neg)^2)) over B*C ----------------
// One wave per (b,c) pair. Lanes 0..49 each load a float2 (covers D=100 floats,
// one coalesced 400B request). Butterfly-reduce, relu, accumulate per wave,
// block-reduce, one atomicAdd per block.
__global__ __launch_bounds__(256) void loss2_kernel(const float* __restrict__ pos,
                                                    const float* __restrict__ neg,
                                                    float* __restrict__ out) {
    const int b    = blockIdx.x;
    const int c0   = blockIdx.y * CBLK;
    const int tid  = threadIdx.x;
    const int lane = tid & 63;
    const int w    = tid >> 6;

    __shared__ float pos_s[DD];
    if (tid < DD) pos_s[tid] = pos[b * DD + tid];
    __syncthreads();

    float p0 = 0.f, p1 = 0.f;
    if (lane < 50) {
        p0 = pos_s[2 * lane];
        p1 = pos_s[2 * lane + 1];
    }

    const float* negb = neg + (size_t)b * ((size_t)CC * DD);
    const int cw = c0 + (w << 6);       // this wave's 64 contiguous c-values
    float acc = 0.f;

    #pragma unroll 2
    for (int i = 0; i < 64; ++i) {
        const int c = cw + i;
        float v0 = 0.f, v1 = 0.f;
        if (lane < 50) {
            const float2 v = *(const float2*)(negb + (size_t)c * DD + 2 * lane);
            v0 = v.x; v1 = v.y;
        }
        const float d0 = p0 - v0;
        const float d1 = p1 - v1;
        float s = d0 * d0 + d1 * d1;    // lanes >= 50 contribute exactly 0
        #pragma unroll
        for (int off = 32; off >= 1; off >>= 1)
            s += __shfl_xor(s, off, 64);
        // all lanes now hold the full sum; only lane 0's acc is used
        acc += fmaxf(MARGIN - s * (1.f / (float)DD), 0.f);
    }

    __shared__ float ws2[4];
    if (lane == 0) ws2[w] = acc;
    __syncthreads();
    if (tid == 0) {
        const float t = ws2[0] + ws2[1] + ws2[2] + ws2[3];
        atomicAdd(out, t * (1.f / ((float)BB * (float)CC)));
    }
}

extern "C" void kernel_launch(void* const* d_in, const int* in_sizes, int n_in,
                              void* d_out, int out_size, void* d_ws, size_t ws_size,
                              hipStream_t stream) {
    const float* pos = (const float*)d_in[0];
    const float* neg = (const float*)d_in[1];
    const float* lan = (const float*)d_in[2];
    float* out = (float*)d_out;

    // loss1 first: it overwrites d_out[0] (handles the 0xAA poison), then
    // loss2 blocks atomicAdd on top. Same stream => ordered.
    loss1_kernel<<<1, 256, 0, stream>>>(pos, lan, out);
    loss2_kernel<<<dim3(BB, CC / CBLK), 256, 0, stream>>>(pos, neg, out);
}

// Round 2
// 573.770 us; speedup vs baseline: 1.0949x; 1.0949x over previous
//
#include <hip/hip_runtime.h>

#define MARGIN 0.1f
#define BB 256
#define CC 4096
#define DD 100
#define TPB 256   // threads per block; grid = (CC/TPB, BB)

// One thread per (b, c) pair. Each thread reads its 400 B neg row as 25
// aligned float4 loads, accumulates the squared distance privately (no
// cross-lane reduction in the hot loop), applies the hinge, and the block
// reduces once at the end -> one atomicAdd per block.
// Blocks with blockIdx.x == 0 additionally fold in their b's slice of loss1.
__global__ __launch_bounds__(TPB) void amloss_kernel(const float* __restrict__ pos,
                                                     const float* __restrict__ neg,
                                                     const float* __restrict__ lan,
                                                     float* __restrict__ out) {
    const int tid = threadIdx.x;
    const int b   = blockIdx.y;
    const int c   = blockIdx.x * TPB + tid;

    // Stage pos[b,:] once; hot-loop reads are wave-uniform broadcasts (free).
    __shared__ __align__(16) float pos_s[DD];
    if (tid < DD) pos_s[tid] = pos[b * DD + tid];
    __syncthreads();

    const float4* __restrict__ row =
        (const float4*)(neg + ((size_t)b * CC + (size_t)c) * DD);
    const float4* __restrict__ pos4 = (const float4*)pos_s;

    float s = 0.f;
    #pragma unroll
    for (int k = 0; k < DD / 4; ++k) {
        const float4 v = row[k];
        const float4 p = pos4[k];   // ds_read_b128 broadcast
        const float d0 = p.x - v.x;
        const float d1 = p.y - v.y;
        const float d2 = p.z - v.z;
        const float d3 = p.w - v.w;
        s += d0 * d0 + d1 * d1 + d2 * d2 + d3 * d3;
    }
    float contrib = fmaxf(MARGIN - s * (1.f / (float)DD), 0.f)
                  * (1.f / ((float)BB * (float)CC));

    // Fused loss1: one block-column (blockIdx.x==0) per b handles 100 elems.
    if (blockIdx.x == 0 && tid < DD) {
        const float d = pos_s[tid] - lan[b * DD + tid];
        contrib += d * d * (1.f / ((float)BB * (float)DD));
    }

    // Block reduction: butterfly within wave, LDS across the 4 waves.
    #pragma unroll
    for (int off = 32; off >= 1; off >>= 1)
        contrib += __shfl_xor(contrib, off, 64);
    __shared__ float ws[4];
    if ((tid & 63) == 0) ws[tid >> 6] = contrib;
    __syncthreads();
    if (tid == 0) atomicAdd(out, ws[0] + ws[1] + ws[2] + ws[3]);
}

extern "C" void kernel_launch(void* const* d_in, const int* in_sizes, int n_in,
                              void* d_out, int out_size, void* d_ws, size_t ws_size,
                              hipStream_t stream) {
    const float* pos = (const float*)d_in[0];
    const float* neg = (const float*)d_in[1];
    const float* lan = (const float*)d_in[2];
    float* out = (float*)d_out;

    // Zero-init output (harness re-poisons to 0xAA); graph-capturable memset.
    hipMemsetAsync(out, 0, (size_t)out_size * sizeof(float), stream);

    amloss_kernel<<<dim3(CC / TPB, BB), TPB, 0, stream>>>(pos, neg, lan, out);
}